// Round 7
// baseline (890.879 us; speedup 1.0000x reference)
//
#include <hip/hip_runtime.h>

#define B 32
#define C 16
#define H 256
#define W 256
#define HID 128
#define HW (H*W)
#define MROWS 32
#define NMM 4096   // minmax blocks: 32*16*(256/32)

typedef __attribute__((ext_vector_type(8))) _Float16 f16x8;
typedef __attribute__((ext_vector_type(4))) float f32x4;

// ---- order-preserving float <-> uint key for atomic min/max ----
__device__ __forceinline__ unsigned fkey(float f){
  unsigned u = __float_as_uint(f);
  return (u & 0x80000000u) ? ~u : (u | 0x80000000u);
}
__device__ __forceinline__ float fkeyinv(unsigned k){
  unsigned u = (k & 0x80000000u) ? (k & 0x7FFFFFFFu) : ~k;
  return __uint_as_float(u);
}
__device__ __forceinline__ int pk2(_Float16 a, _Float16 b){
  union { _Float16 h[2]; int i; } u; u.h[0]=a; u.h[1]=b; return u.i;
}

// ---- fused prep (weight fragments) + per-channel Sobel min/max ----
// mm layout: [0..15]=gx_min [16..31]=gy_min [32..47]=gx_max [48..63]=gy_max
// (mins pre-set to 0xFFFFFFFF, maxs to 0x00000000 via hipMemsetAsync)
__global__ __launch_bounds__(64) void k_pm(
    const float* __restrict__ x, const float* __restrict__ w1,
    const float* __restrict__ w2, unsigned* __restrict__ mm,
    _Float16* __restrict__ w1kh, _Float16* __restrict__ w1kl,
    _Float16* __restrict__ w2h,  _Float16* __restrict__ w2l)
{
  const int tid = threadIdx.x;
  if (blockIdx.x >= NMM){
    // ---- weight prep: fragment-ordered fp16 hi/lo, K padded to 64 ----
    // x32 A frag: lane l holds M=l&15, K=kb*32 + 8*(l>>4) + j
    int e = (blockIdx.x - NMM)*64 + tid;
    if (e < 8192){
      int j = e & 7, l = (e >> 3) & 63, otk = e >> 9;   // otk = ot*2+kb
      int o = 16*(otk >> 1) + (l & 15);
      int k = (otk & 1)*32 + 8*(l >> 4) + j;
      float v = (k < 48) ? w1[o*48 + k] : 0.f;
      _Float16 h = (_Float16)v;
      w1kh[e] = h; w1kl[e] = (_Float16)(v - (float)h);
    } else {
      int e2 = e - 8192;
      int j = e2 & 7, l = (e2 >> 3) & 63, s = e2 >> 9;
      float v = w2[(l & 15)*128 + 32*s + 8*(l >> 4) + j];
      _Float16 h = (_Float16)v;
      w2h[e2] = h; w2l[e2] = (_Float16)(v - (float)h);
    }
    return;
  }
  // ---- minmax: 1 wave, thread = 4 pixels, float4 rows + shfl halo ----
  int chunk = blockIdx.x & 7, bc = blockIdx.x >> 3, c = bc & 15;
  const float* p = x + (size_t)bc * HW;
  const int j4 = tid * 4;
  const int i0 = chunk * MROWS;

  float Aw[6], Bw[6], Cw[6];
  auto loadrow = [&](int row, float* wv){
    float4 v = *(const float4*)(p + (size_t)row*W + j4);
    float l = __shfl(v.w, tid - 1);
    float r = __shfl(v.x, tid + 1);
    if (tid == 0)  l = 0.f;
    if (tid == 63) r = 0.f;
    wv[0]=l; wv[1]=v.x; wv[2]=v.y; wv[3]=v.z; wv[4]=v.w; wv[5]=r;
  };
  if (i0 > 0) loadrow(i0-1, Aw);
  else { for (int t=0;t<6;++t) Aw[t]=0.f; }
  loadrow(i0, Bw);

  float gxmn = 1e30f, gxmx = -1e30f, gymn = 1e30f, gymx = -1e30f;
  for (int r = 0; r < MROWS; ++r){
    int ipr = i0 + r + 1;
    if (ipr < H) loadrow(ipr, Cw);
    else { for (int t=0;t<6;++t) Cw[t]=0.f; }
    #pragma unroll
    for (int t = 0; t < 4; ++t){
      float gx = (Aw[t+2]-Aw[t] + 2.f*(Bw[t+2]-Bw[t]) + Cw[t+2]-Cw[t]) * 0.125f;
      float gy = (Cw[t]-Aw[t] + 2.f*(Cw[t+1]-Aw[t+1]) + Cw[t+2]-Aw[t+2]) * 0.125f;
      gxmn = fminf(gxmn, gx); gxmx = fmaxf(gxmx, gx);
      gymn = fminf(gymn, gy); gymx = fmaxf(gymx, gy);
    }
    #pragma unroll
    for (int t = 0; t < 6; ++t){ Aw[t] = Bw[t]; Bw[t] = Cw[t]; }
  }
  for (int off = 32; off; off >>= 1){
    gxmn = fminf(gxmn, __shfl_down(gxmn, off));
    gxmx = fmaxf(gxmx, __shfl_down(gxmx, off));
    gymn = fminf(gymn, __shfl_down(gymn, off));
    gymx = fmaxf(gymx, __shfl_down(gymx, off));
  }
  if (tid == 0){
    atomicMin(&mm[c],      fkey(gxmn));
    atomicMin(&mm[16+c],   fkey(gymn));
    atomicMax(&mm[32+c],   fkey(gxmx));
    atomicMax(&mm[48+c],   fkey(gymx));
  }
}

// ---- main: 1 wave per 64 pixels; stencil -> swizzled LDS -> MFMA MLP ----
__global__ __launch_bounds__(64, 3) void k_main(
    const float* __restrict__ x, const float* __restrict__ mrand,
    const unsigned* __restrict__ mm,
    const _Float16* __restrict__ w1kh, const _Float16* __restrict__ w1kl,
    const _Float16* __restrict__ w2h,  const _Float16* __restrict__ w2l,
    const float* __restrict__ b1,
    float* __restrict__ out, float* __restrict__ alpha_new,
    unsigned char* __restrict__ premask)
{
  // row = 16 chunks of 16B, XOR-swizzled: phys = chunk ^ (px&15).
  // chunks 0..5: y hi (48 f16); 6..11: y lo; 12..15: x[0..15] as fp32.
  __shared__ __align__(16) _Float16 yl[64][128];    // 16 KB
  __shared__ float amn_x[16], inv_x[16], amn_y[16], inv_y[16];

  const int tid = threadIdx.x;
  // XCD-contiguous swizzle: each XCD gets 4096 consecutive blocks (1024 rows)
  const int bswz = (blockIdx.x & 7)*4096 + (blockIdx.x >> 3);
  const int quarter = bswz & 3;
  const int rowid = bswz >> 2;
  const int i = rowid & 255, b = rowid >> 8;
  const int j0 = quarter << 6;
  const int q = tid >> 4, n16 = tid & 15;
  const int key = n16;                      // swizzle key (= tid&15 = n16)

  if (tid < 16){
    int c = tid;
    float mn = fabsf(fkeyinv(mm[c]));
    float mx = fabsf(fkeyinv(mm[32+c]));
    float dv = mn + mx;
    amn_x[c] = mn; inv_x[c] = (dv == 0.f) ? 1.f : 1.f/dv;
    mn = fabsf(fkeyinv(mm[16+c]));
    mx = fabsf(fkeyinv(mm[48+c]));
    dv = mn + mx;
    amn_y[c] = mn; inv_y[c] = (dv == 0.f) ? 1.f : 1.f/dv;
  }
  // single-wave block: LDS ops are program-ordered, no barrier needed

  // ---- stencil: thread = pixel j0+tid ----
  {
    const float* xb = x + (size_t)b * C * HW;
    const int j = j0 + tid;
    const int im = i-1, ipp = i+1;
    const bool iu = im >= 0, id = ipp < H, jl = j > 0, jr = j < W-1;
    float yv[48];
    float pre3 = 0.f;
    #pragma unroll
    for (int c = 0; c < 16; ++c){
      const float* pc = xb + (size_t)c * HW;
      const float* r0 = pc + (size_t)im*W;
      const float* r1 = pc + (size_t)i*W;
      const float* r2 = pc + (size_t)ipp*W;
      float v00 = (iu&&jl) ? r0[j-1] : 0.f;
      float v01 =  iu      ? r0[j]   : 0.f;
      float v02 = (iu&&jr) ? r0[j+1] : 0.f;
      float v10 =  jl      ? r1[j-1] : 0.f;
      float v11 =            r1[j];
      float v12 =  jr      ? r1[j+1] : 0.f;
      float v20 = (id&&jl) ? r2[j-1] : 0.f;
      float v21 =  id      ? r2[j]   : 0.f;
      float v22 = (id&&jr) ? r2[j+1] : 0.f;
      float gx = (v02 - v00 + 2.f*(v12 - v10) + v22 - v20) * 0.125f;
      float gy = (v20 - v00 + 2.f*(v21 - v01) + v22 - v02) * 0.125f;
      float gl = (v01 + v10 + v12 + v21 - 4.f*v11) * 0.125f;
      float gxn = (gx + amn_x[c]) * inv_x[c];
      float gyn = (gy + amn_y[c]) * inv_y[c];
      yv[c]    = v11;
      yv[16+c] = gl;
      yv[32+c] = sqrtf(gxn*gxn + gyn*gyn);
      if (c == 3){
        pre3 = fmaxf(fmaxf(fmaxf(v00,v01),fmaxf(v02,v10)),
               fmaxf(fmaxf(v11,v12),fmaxf(fmaxf(v20,v21),v22)));
      }
    }
    premask[(size_t)b*HW + (size_t)i*W + j] = (pre3 > 0.1f) ? 1 : 0;
    // write y hi/lo + xc(fp32) chunks, swizzled
    #pragma unroll
    for (int cb = 0; cb < 6; ++cb){
      f16x8 vh, vl;
      #pragma unroll
      for (int e = 0; e < 8; ++e){
        float v = yv[cb*8+e];
        _Float16 h = (_Float16)v;
        vh[e] = h; vl[e] = (_Float16)(v - (float)h);
      }
      *(f16x8*)&yl[tid][((cb    ) ^ key)*8] = vh;
      *(f16x8*)&yl[tid][((cb + 6) ^ key)*8] = vl;
    }
    #pragma unroll
    for (int t = 0; t < 4; ++t){
      union { float f[4]; f16x8 v; } u;
      #pragma unroll
      for (int e = 0; e < 4; ++e) u.f[e] = yv[4*t+e];
      *(f16x8*)&yl[tid][((12+t) ^ key)*8] = u.v;
    }
  }

  // ---- resident A2 fragments ----
  f16x8 A2h[4], A2l[4];
  #pragma unroll
  for (int s = 0; s < 4; ++s){
    A2h[s] = *(const f16x8*)(w2h + s*512 + tid*8);
    A2l[s] = *(const f16x8*)(w2l + s*512 + tid*8);
  }

  const size_t rowbase = (size_t)b*C*HW + (size_t)i*W;
  const size_t abase   = (size_t)b*HW + (size_t)i*W;
  const float* mr_row  = mrand + abase + j0;
  const int srcA = 32*(q&1) + n16;
  const bool hiq = (q >= 2);

  // ---- 4 groups of 16 pixels ----
  #pragma unroll 1
  for (int g = 0; g < 4; ++g){
    const int p = g*16 + n16;                 // local pixel / LDS row
    const _Float16* yr = yl[p];
    f16x8 Bh0 = *(const f16x8*)&yr[(( q       ) ^ key)*8];
    f16x8 Bl0 = *(const f16x8*)&yr[(( 6+q     ) ^ key)*8];
    // k>=48 has zero A-side weights; q>=2 lanes re-read a finite chunk (harmless)
    f16x8 Bh1 = *(const f16x8*)&yr[(( 4+(q&1) ) ^ key)*8];
    f16x8 Bl1 = *(const f16x8*)&yr[((10+(q&1) ) ^ key)*8];

    // GEMM1: h = relu(w1*y + b1), 4-product hi/lo (fp32 fidelity)
    int hh[8][2], hl[8][2];
    #pragma unroll
    for (int ot = 0; ot < 8; ++ot){
      const f16x8 Ah0 = *(const f16x8*)(w1kh + (ot*2  )*512 + tid*8);
      const f16x8 Ah1 = *(const f16x8*)(w1kh + (ot*2+1)*512 + tid*8);
      const f16x8 Al0 = *(const f16x8*)(w1kl + (ot*2  )*512 + tid*8);
      const f16x8 Al1 = *(const f16x8*)(w1kl + (ot*2+1)*512 + tid*8);
      f32x4 acc = *(const f32x4*)(b1 + 16*ot + 4*q);
      acc = __builtin_amdgcn_mfma_f32_16x16x32_f16(Ah0, Bh0, acc, 0, 0, 0);
      acc = __builtin_amdgcn_mfma_f32_16x16x32_f16(Ah0, Bl0, acc, 0, 0, 0);
      acc = __builtin_amdgcn_mfma_f32_16x16x32_f16(Al0, Bh0, acc, 0, 0, 0);
      acc = __builtin_amdgcn_mfma_f32_16x16x32_f16(Al0, Bl0, acc, 0, 0, 0);
      acc = __builtin_amdgcn_mfma_f32_16x16x32_f16(Ah1, Bh1, acc, 0, 0, 0);
      acc = __builtin_amdgcn_mfma_f32_16x16x32_f16(Ah1, Bl1, acc, 0, 0, 0);
      acc = __builtin_amdgcn_mfma_f32_16x16x32_f16(Al1, Bh1, acc, 0, 0, 0);
      acc = __builtin_amdgcn_mfma_f32_16x16x32_f16(Al1, Bl1, acc, 0, 0, 0);
      float h0 = fmaxf(acc[0],0.f), h1 = fmaxf(acc[1],0.f);
      float h2 = fmaxf(acc[2],0.f), h3 = fmaxf(acc[3],0.f);
      _Float16 a0=(_Float16)h0, a1=(_Float16)h1, a2=(_Float16)h2, a3=(_Float16)h3;
      hh[ot][0] = pk2(a0, a1);
      hh[ot][1] = pk2(a2, a3);
      hl[ot][0] = pk2((_Float16)(h0-(float)a0), (_Float16)(h1-(float)a1));
      hl[ot][1] = pk2((_Float16)(h2-(float)a2), (_Float16)(h3-(float)a3));
    }

    // GEMM2: dx = w2*h; B-fragments built via in-wave shuffles (no LDS)
    f32x4 d2 = {0.f, 0.f, 0.f, 0.f};
    #pragma unroll
    for (int s = 0; s < 4; ++s){
      int e0 = __shfl(hh[2*s  ][0], srcA),    e1 = __shfl(hh[2*s  ][1], srcA);
      int f0 = __shfl(hh[2*s+1][0], srcA),    f1 = __shfl(hh[2*s+1][1], srcA);
      int g0 = __shfl(hh[2*s  ][0], srcA+16), g1 = __shfl(hh[2*s  ][1], srcA+16);
      int k0 = __shfl(hh[2*s+1][0], srcA+16), k1 = __shfl(hh[2*s+1][1], srcA+16);
      union { int d[4]; f16x8 v; } bh;
      bh.d[0] = hiq ? f0 : e0; bh.d[1] = hiq ? f1 : e1;
      bh.d[2] = hiq ? k0 : g0; bh.d[3] = hiq ? k1 : g1;
      e0 = __shfl(hl[2*s  ][0], srcA);    e1 = __shfl(hl[2*s  ][1], srcA);
      f0 = __shfl(hl[2*s+1][0], srcA);    f1 = __shfl(hl[2*s+1][1], srcA);
      g0 = __shfl(hl[2*s  ][0], srcA+16); g1 = __shfl(hl[2*s  ][1], srcA+16);
      k0 = __shfl(hl[2*s+1][0], srcA+16); k1 = __shfl(hl[2*s+1][1], srcA+16);
      union { int d[4]; f16x8 v; } bl;
      bl.d[0] = hiq ? f0 : e0; bl.d[1] = hiq ? f1 : e1;
      bl.d[2] = hiq ? k0 : g0; bl.d[3] = hiq ? k1 : g1;
      d2 = __builtin_amdgcn_mfma_f32_16x16x32_f16(A2h[s], bh.v, d2, 0, 0, 0);
      d2 = __builtin_amdgcn_mfma_f32_16x16x32_f16(A2h[s], bl.v, d2, 0, 0, 0);
      d2 = __builtin_amdgcn_mfma_f32_16x16x32_f16(A2l[s], bh.v, d2, 0, 0, 0);
      d2 = __builtin_amdgcn_mfma_f32_16x16x32_f16(A2l[s], bl.v, d2, 0, 0, 0);
    }

    // epilogue: exact fp32 x from LDS chunks 12..15
    union { f16x8 v; float f[4]; } xu;
    xu.v = *(const f16x8*)&yr[((12+q) ^ key)*8];
    const float fire = (mr_row[p] <= 0.5f) ? 1.f : 0.f;
    #pragma unroll
    for (int r = 0; r < 4; ++r)
      out[rowbase + (size_t)(4*q+r)*HW + (j0 + p)] = xu.f[r] + d2[r]*fire;
    if (q == 0) alpha_new[abase + j0 + p] = xu.f[3] + d2[3]*fire;
  }
}

// ---- life: pre-mask (from k_main) AND pooled(alpha_new) > 0.1 ----
__global__ __launch_bounds__(256) void k_life(
    const float* __restrict__ alpha_new,
    const unsigned char* __restrict__ premask,
    float* __restrict__ out)
{
  __shared__ float lds[258];
  const int i = blockIdx.x & 255, b = blockIdx.x >> 8;
  const int j = threadIdx.x;
  const float* an = alpha_new + (size_t)b*HW;
  float m = an[(size_t)i*W + j];
  if (i > 0)   m = fmaxf(m, an[(size_t)(i-1)*W + j]);
  if (i < 255) m = fmaxf(m, an[(size_t)(i+1)*W + j]);
  if (j == 0){ lds[0] = 0.f; lds[257] = 0.f; }
  lds[j+1] = m;
  __syncthreads();
  float pooled = fmaxf(fmaxf(lds[j], lds[j+1]), lds[j+2]);
  bool life = (premask[(size_t)b*HW + (size_t)i*W + j] != 0) && (pooled > 0.1f);
  if (!life){
    size_t px = (size_t)b*C*HW + (size_t)i*W + j;
    #pragma unroll
    for (int c = 0; c < 16; ++c) out[px + (size_t)c*HW] = 0.f;
  }
}

extern "C" void kernel_launch(void* const* d_in, const int* in_sizes, int n_in,
                              void* d_out, int out_size, void* d_ws, size_t ws_size,
                              hipStream_t stream) {
  const float* x  = (const float*)d_in[0];
  const float* w1 = (const float*)d_in[1];
  const float* b1 = (const float*)d_in[2];
  const float* w2 = (const float*)d_in[3];
  const float* mr = (const float*)d_in[4];

  char* ws = (char*)d_ws;
  unsigned* mm          = (unsigned*)ws;                          // 256 B
  float* alpha_n        = (float*)(ws + 256);                     // 8 MB
  unsigned char* pmask  = (unsigned char*)(ws + 256 + 8388608);   // 2 MB
  char* wb              = ws + 256 + 8388608 + 2097152;
  _Float16* w1kh = (_Float16*)(wb);                               // 16 KB
  _Float16* w1kl = (_Float16*)(wb + 16384);                       // 16 KB
  _Float16* w2h  = (_Float16*)(wb + 32768);                       //  4 KB
  _Float16* w2l  = (_Float16*)(wb + 36864);                       //  4 KB
  float* out = (float*)d_out;

  (void)hipMemsetAsync(mm, 0xFF, 128, stream);                // mins  -> +inf key
  (void)hipMemsetAsync((char*)mm + 128, 0x00, 128, stream);   // maxs  -> -inf key
  k_pm  <<<NMM + 160, 64, 0, stream>>>(x, w1, w2, mm, w1kh, w1kl, w2h, w2l);
  k_main<<<B*H*4, 64, 0, stream>>>(x, mr, mm, w1kh, w1kl, w2h, w2l, b1,
                                   out, alpha_n, pmask);
  k_life<<<B*H, 256, 0, stream>>>(alpha_n, pmask, out);
}

// Round 8
// 879.718 us; speedup vs baseline: 1.0127x; 1.0127x over previous
//
#include <hip/hip_runtime.h>

#define B 32
#define C 16
#define H 256
#define W 256
#define HID 128
#define HW (H*W)
#define MROWS 32
#define NMM 4096   // minmax blocks: 32*16*(256/32)

typedef __attribute__((ext_vector_type(8))) _Float16 f16x8;
typedef __attribute__((ext_vector_type(4))) float f32x4;

// ---- order-preserving float <-> uint key for atomic min/max ----
__device__ __forceinline__ unsigned fkey(float f){
  unsigned u = __float_as_uint(f);
  return (u & 0x80000000u) ? ~u : (u | 0x80000000u);
}
__device__ __forceinline__ float fkeyinv(unsigned k){
  unsigned u = (k & 0x80000000u) ? (k & 0x7FFFFFFFu) : ~k;
  return __uint_as_float(u);
}
__device__ __forceinline__ int pk2(_Float16 a, _Float16 b){
  union { _Float16 h[2]; int i; } u; u.h[0]=a; u.h[1]=b; return u.i;
}

// ---- fused prep (weight fragments) + per-channel Sobel min/max ----
// mm layout: [0..15]=gx_min [16..31]=gy_min [32..47]=gx_max [48..63]=gy_max
// (mins pre-set to 0xFFFFFFFF, maxs to 0x00000000 via hipMemsetAsync)
__global__ __launch_bounds__(64) void k_pm(
    const float* __restrict__ x, const float* __restrict__ w1,
    const float* __restrict__ w2, unsigned* __restrict__ mm,
    _Float16* __restrict__ w1kh, _Float16* __restrict__ w1kl,
    _Float16* __restrict__ w2h,  _Float16* __restrict__ w2l)
{
  const int tid = threadIdx.x;
  if (blockIdx.x >= NMM){
    // ---- weight prep: fragment-ordered fp16 hi/lo, K padded to 64 ----
    // x32 A frag: lane l holds M=l&15, K=kb*32 + 8*(l>>4) + j
    int e = (blockIdx.x - NMM)*64 + tid;
    if (e < 8192){
      int j = e & 7, l = (e >> 3) & 63, otk = e >> 9;   // otk = ot*2+kb
      int o = 16*(otk >> 1) + (l & 15);
      int k = (otk & 1)*32 + 8*(l >> 4) + j;
      float v = (k < 48) ? w1[o*48 + k] : 0.f;
      _Float16 h = (_Float16)v;
      w1kh[e] = h; w1kl[e] = (_Float16)(v - (float)h);
    } else {
      int e2 = e - 8192;
      int j = e2 & 7, l = (e2 >> 3) & 63, s = e2 >> 9;
      float v = w2[(l & 15)*128 + 32*s + 8*(l >> 4) + j];
      _Float16 h = (_Float16)v;
      w2h[e2] = h; w2l[e2] = (_Float16)(v - (float)h);
    }
    return;
  }
  // ---- minmax: 1 wave, thread = 4 pixels, float4 rows + shfl halo ----
  int chunk = blockIdx.x & 7, bc = blockIdx.x >> 3, c = bc & 15;
  const float* p = x + (size_t)bc * HW;
  const int j4 = tid * 4;
  const int i0 = chunk * MROWS;

  float Aw[6], Bw[6], Cw[6];
  auto loadrow = [&](int row, float* wv){
    float4 v = *(const float4*)(p + (size_t)row*W + j4);
    float l = __shfl(v.w, tid - 1);
    float r = __shfl(v.x, tid + 1);
    if (tid == 0)  l = 0.f;
    if (tid == 63) r = 0.f;
    wv[0]=l; wv[1]=v.x; wv[2]=v.y; wv[3]=v.z; wv[4]=v.w; wv[5]=r;
  };
  if (i0 > 0) loadrow(i0-1, Aw);
  else { for (int t=0;t<6;++t) Aw[t]=0.f; }
  loadrow(i0, Bw);

  float gxmn = 1e30f, gxmx = -1e30f, gymn = 1e30f, gymx = -1e30f;
  for (int r = 0; r < MROWS; ++r){
    int ipr = i0 + r + 1;
    if (ipr < H) loadrow(ipr, Cw);
    else { for (int t=0;t<6;++t) Cw[t]=0.f; }
    #pragma unroll
    for (int t = 0; t < 4; ++t){
      float gx = (Aw[t+2]-Aw[t] + 2.f*(Bw[t+2]-Bw[t]) + Cw[t+2]-Cw[t]) * 0.125f;
      float gy = (Cw[t]-Aw[t] + 2.f*(Cw[t+1]-Aw[t+1]) + Cw[t+2]-Aw[t+2]) * 0.125f;
      gxmn = fminf(gxmn, gx); gxmx = fmaxf(gxmx, gx);
      gymn = fminf(gymn, gy); gymx = fmaxf(gymx, gy);
    }
    #pragma unroll
    for (int t = 0; t < 6; ++t){ Aw[t] = Bw[t]; Bw[t] = Cw[t]; }
  }
  for (int off = 32; off; off >>= 1){
    gxmn = fminf(gxmn, __shfl_down(gxmn, off));
    gxmx = fmaxf(gxmx, __shfl_down(gxmx, off));
    gymn = fminf(gymn, __shfl_down(gymn, off));
    gymx = fmaxf(gymx, __shfl_down(gymx, off));
  }
  if (tid == 0){
    atomicMin(&mm[c],      fkey(gxmn));
    atomicMin(&mm[16+c],   fkey(gymn));
    atomicMax(&mm[32+c],   fkey(gxmx));
    atomicMax(&mm[48+c],   fkey(gymx));
  }
}

// ---- main: 1 wave per 64 pixels; stencil -> swizzled LDS -> MFMA MLP ----
__global__ __launch_bounds__(64, 3) void k_main(
    const float* __restrict__ x, const float* __restrict__ mrand,
    const unsigned* __restrict__ mm,
    const _Float16* __restrict__ w1kh, const _Float16* __restrict__ w1kl,
    const _Float16* __restrict__ w2h,  const _Float16* __restrict__ w2l,
    const float* __restrict__ b1,
    float* __restrict__ out, float* __restrict__ alpha_new,
    unsigned char* __restrict__ premask)
{
  // row = 16 chunks of 16B, XOR-swizzled: phys = chunk ^ (px&15).
  // chunks 0..5: y hi (48 f16); 6..11: y lo; 12..15: x[0..15] as fp32.
  __shared__ __align__(16) _Float16 yl[64][128];    // 16 KB
  __shared__ float amn_x[16], inv_x[16], amn_y[16], inv_y[16];

  const int tid = threadIdx.x;
  // natural dispatch order (round-5-proven L2 locality; XCD swizzle REMOVED:
  // it caused 8x fetch+write amplification in round 7)
  const int bswz = blockIdx.x;
  const int quarter = bswz & 3;
  const int rowid = bswz >> 2;
  const int i = rowid & 255, b = rowid >> 8;
  const int j0 = quarter << 6;
  const int q = tid >> 4, n16 = tid & 15;
  const int key = n16;                      // swizzle key (= tid&15 = n16)

  if (tid < 16){
    int c = tid;
    float mn = fabsf(fkeyinv(mm[c]));
    float mx = fabsf(fkeyinv(mm[32+c]));
    float dv = mn + mx;
    amn_x[c] = mn; inv_x[c] = (dv == 0.f) ? 1.f : 1.f/dv;
    mn = fabsf(fkeyinv(mm[16+c]));
    mx = fabsf(fkeyinv(mm[48+c]));
    dv = mn + mx;
    amn_y[c] = mn; inv_y[c] = (dv == 0.f) ? 1.f : 1.f/dv;
  }
  // single-wave block: LDS ops are program-ordered, no barrier needed

  // ---- stencil: thread = pixel j0+tid ----
  {
    const float* xb = x + (size_t)b * C * HW;
    const int j = j0 + tid;
    const int im = i-1, ipp = i+1;
    const bool iu = im >= 0, id = ipp < H, jl = j > 0, jr = j < W-1;
    float yv[48];
    float pre3 = 0.f;
    #pragma unroll
    for (int c = 0; c < 16; ++c){
      const float* pc = xb + (size_t)c * HW;
      const float* r0 = pc + (size_t)im*W;
      const float* r1 = pc + (size_t)i*W;
      const float* r2 = pc + (size_t)ipp*W;
      float v00 = (iu&&jl) ? r0[j-1] : 0.f;
      float v01 =  iu      ? r0[j]   : 0.f;
      float v02 = (iu&&jr) ? r0[j+1] : 0.f;
      float v10 =  jl      ? r1[j-1] : 0.f;
      float v11 =            r1[j];
      float v12 =  jr      ? r1[j+1] : 0.f;
      float v20 = (id&&jl) ? r2[j-1] : 0.f;
      float v21 =  id      ? r2[j]   : 0.f;
      float v22 = (id&&jr) ? r2[j+1] : 0.f;
      float gx = (v02 - v00 + 2.f*(v12 - v10) + v22 - v20) * 0.125f;
      float gy = (v20 - v00 + 2.f*(v21 - v01) + v22 - v02) * 0.125f;
      float gl = (v01 + v10 + v12 + v21 - 4.f*v11) * 0.125f;
      float gxn = (gx + amn_x[c]) * inv_x[c];
      float gyn = (gy + amn_y[c]) * inv_y[c];
      yv[c]    = v11;
      yv[16+c] = gl;
      yv[32+c] = sqrtf(gxn*gxn + gyn*gyn);
      if (c == 3){
        pre3 = fmaxf(fmaxf(fmaxf(v00,v01),fmaxf(v02,v10)),
               fmaxf(fmaxf(v11,v12),fmaxf(fmaxf(v20,v21),v22)));
      }
    }
    premask[(size_t)b*HW + (size_t)i*W + j] = (pre3 > 0.1f) ? 1 : 0;
    // write y hi/lo + xc(fp32) chunks, swizzled
    #pragma unroll
    for (int cb = 0; cb < 6; ++cb){
      f16x8 vh, vl;
      #pragma unroll
      for (int e = 0; e < 8; ++e){
        float v = yv[cb*8+e];
        _Float16 h = (_Float16)v;
        vh[e] = h; vl[e] = (_Float16)(v - (float)h);
      }
      *(f16x8*)&yl[tid][((cb    ) ^ key)*8] = vh;
      *(f16x8*)&yl[tid][((cb + 6) ^ key)*8] = vl;
    }
    #pragma unroll
    for (int t = 0; t < 4; ++t){
      union { float f[4]; f16x8 v; } u;
      #pragma unroll
      for (int e = 0; e < 4; ++e) u.f[e] = yv[4*t+e];
      *(f16x8*)&yl[tid][((12+t) ^ key)*8] = u.v;
    }
  }

  // ---- resident A2 fragments ----
  f16x8 A2h[4], A2l[4];
  #pragma unroll
  for (int s = 0; s < 4; ++s){
    A2h[s] = *(const f16x8*)(w2h + s*512 + tid*8);
    A2l[s] = *(const f16x8*)(w2l + s*512 + tid*8);
  }

  const size_t rowbase = (size_t)b*C*HW + (size_t)i*W;
  const size_t abase   = (size_t)b*HW + (size_t)i*W;
  const float* mr_row  = mrand + abase + j0;
  const int srcA = 32*(q&1) + n16;
  const bool hiq = (q >= 2);

  // ---- 4 groups of 16 pixels ----
  #pragma unroll 1
  for (int g = 0; g < 4; ++g){
    const int p = g*16 + n16;                 // local pixel / LDS row
    const _Float16* yr = yl[p];
    f16x8 Bh0 = *(const f16x8*)&yr[(( q       ) ^ key)*8];
    f16x8 Bl0 = *(const f16x8*)&yr[(( 6+q     ) ^ key)*8];
    // k>=48 has zero A-side weights; q>=2 lanes re-read a finite chunk (harmless)
    f16x8 Bh1 = *(const f16x8*)&yr[(( 4+(q&1) ) ^ key)*8];
    f16x8 Bl1 = *(const f16x8*)&yr[((10+(q&1) ) ^ key)*8];

    // GEMM1: h = relu(w1*y + b1), 4-product hi/lo (fp32 fidelity)
    int hh[8][2], hl[8][2];
    #pragma unroll
    for (int ot = 0; ot < 8; ++ot){
      const f16x8 Ah0 = *(const f16x8*)(w1kh + (ot*2  )*512 + tid*8);
      const f16x8 Ah1 = *(const f16x8*)(w1kh + (ot*2+1)*512 + tid*8);
      const f16x8 Al0 = *(const f16x8*)(w1kl + (ot*2  )*512 + tid*8);
      const f16x8 Al1 = *(const f16x8*)(w1kl + (ot*2+1)*512 + tid*8);
      f32x4 acc = *(const f32x4*)(b1 + 16*ot + 4*q);
      acc = __builtin_amdgcn_mfma_f32_16x16x32_f16(Ah0, Bh0, acc, 0, 0, 0);
      acc = __builtin_amdgcn_mfma_f32_16x16x32_f16(Ah0, Bl0, acc, 0, 0, 0);
      acc = __builtin_amdgcn_mfma_f32_16x16x32_f16(Al0, Bh0, acc, 0, 0, 0);
      acc = __builtin_amdgcn_mfma_f32_16x16x32_f16(Al0, Bl0, acc, 0, 0, 0);
      acc = __builtin_amdgcn_mfma_f32_16x16x32_f16(Ah1, Bh1, acc, 0, 0, 0);
      acc = __builtin_amdgcn_mfma_f32_16x16x32_f16(Ah1, Bl1, acc, 0, 0, 0);
      acc = __builtin_amdgcn_mfma_f32_16x16x32_f16(Al1, Bh1, acc, 0, 0, 0);
      acc = __builtin_amdgcn_mfma_f32_16x16x32_f16(Al1, Bl1, acc, 0, 0, 0);
      float h0 = fmaxf(acc[0],0.f), h1 = fmaxf(acc[1],0.f);
      float h2 = fmaxf(acc[2],0.f), h3 = fmaxf(acc[3],0.f);
      _Float16 a0=(_Float16)h0, a1=(_Float16)h1, a2=(_Float16)h2, a3=(_Float16)h3;
      hh[ot][0] = pk2(a0, a1);
      hh[ot][1] = pk2(a2, a3);
      hl[ot][0] = pk2((_Float16)(h0-(float)a0), (_Float16)(h1-(float)a1));
      hl[ot][1] = pk2((_Float16)(h2-(float)a2), (_Float16)(h3-(float)a3));
    }

    // GEMM2: dx = w2*h; B-fragments built via in-wave shuffles (no LDS)
    f32x4 d2 = {0.f, 0.f, 0.f, 0.f};
    #pragma unroll
    for (int s = 0; s < 4; ++s){
      int e0 = __shfl(hh[2*s  ][0], srcA),    e1 = __shfl(hh[2*s  ][1], srcA);
      int f0 = __shfl(hh[2*s+1][0], srcA),    f1 = __shfl(hh[2*s+1][1], srcA);
      int g0 = __shfl(hh[2*s  ][0], srcA+16), g1 = __shfl(hh[2*s  ][1], srcA+16);
      int k0 = __shfl(hh[2*s+1][0], srcA+16), k1 = __shfl(hh[2*s+1][1], srcA+16);
      union { int d[4]; f16x8 v; } bh;
      bh.d[0] = hiq ? f0 : e0; bh.d[1] = hiq ? f1 : e1;
      bh.d[2] = hiq ? k0 : g0; bh.d[3] = hiq ? k1 : g1;
      e0 = __shfl(hl[2*s  ][0], srcA);    e1 = __shfl(hl[2*s  ][1], srcA);
      f0 = __shfl(hl[2*s+1][0], srcA);    f1 = __shfl(hl[2*s+1][1], srcA);
      g0 = __shfl(hl[2*s  ][0], srcA+16); g1 = __shfl(hl[2*s  ][1], srcA+16);
      k0 = __shfl(hl[2*s+1][0], srcA+16); k1 = __shfl(hl[2*s+1][1], srcA+16);
      union { int d[4]; f16x8 v; } bl;
      bl.d[0] = hiq ? f0 : e0; bl.d[1] = hiq ? f1 : e1;
      bl.d[2] = hiq ? k0 : g0; bl.d[3] = hiq ? k1 : g1;
      d2 = __builtin_amdgcn_mfma_f32_16x16x32_f16(A2h[s], bh.v, d2, 0, 0, 0);
      d2 = __builtin_amdgcn_mfma_f32_16x16x32_f16(A2h[s], bl.v, d2, 0, 0, 0);
      d2 = __builtin_amdgcn_mfma_f32_16x16x32_f16(A2l[s], bh.v, d2, 0, 0, 0);
      d2 = __builtin_amdgcn_mfma_f32_16x16x32_f16(A2l[s], bl.v, d2, 0, 0, 0);
    }

    // epilogue: exact fp32 x from LDS chunks 12..15
    union { f16x8 v; float f[4]; } xu;
    xu.v = *(const f16x8*)&yr[((12+q) ^ key)*8];
    const float fire = (mr_row[p] <= 0.5f) ? 1.f : 0.f;
    #pragma unroll
    for (int r = 0; r < 4; ++r)
      out[rowbase + (size_t)(4*q+r)*HW + (j0 + p)] = xu.f[r] + d2[r]*fire;
    if (q == 0) alpha_new[abase + j0 + p] = xu.f[3] + d2[3]*fire;
  }
}

// ---- life: pre-mask (from k_main) AND pooled(alpha_new) > 0.1 ----
__global__ __launch_bounds__(256) void k_life(
    const float* __restrict__ alpha_new,
    const unsigned char* __restrict__ premask,
    float* __restrict__ out)
{
  __shared__ float lds[258];
  const int i = blockIdx.x & 255, b = blockIdx.x >> 8;
  const int j = threadIdx.x;
  const float* an = alpha_new + (size_t)b*HW;
  float m = an[(size_t)i*W + j];
  if (i > 0)   m = fmaxf(m, an[(size_t)(i-1)*W + j]);
  if (i < 255) m = fmaxf(m, an[(size_t)(i+1)*W + j]);
  if (j == 0){ lds[0] = 0.f; lds[257] = 0.f; }
  lds[j+1] = m;
  __syncthreads();
  float pooled = fmaxf(fmaxf(lds[j], lds[j+1]), lds[j+2]);
  bool life = (premask[(size_t)b*HW + (size_t)i*W + j] != 0) && (pooled > 0.1f);
  if (!life){
    size_t px = (size_t)b*C*HW + (size_t)i*W + j;
    #pragma unroll
    for (int c = 0; c < 16; ++c) out[px + (size_t)c*HW] = 0.f;
  }
}

extern "C" void kernel_launch(void* const* d_in, const int* in_sizes, int n_in,
                              void* d_out, int out_size, void* d_ws, size_t ws_size,
                              hipStream_t stream) {
  const float* x  = (const float*)d_in[0];
  const float* w1 = (const float*)d_in[1];
  const float* b1 = (const float*)d_in[2];
  const float* w2 = (const float*)d_in[3];
  const float* mr = (const float*)d_in[4];

  char* ws = (char*)d_ws;
  unsigned* mm          = (unsigned*)ws;                          // 256 B
  float* alpha_n        = (float*)(ws + 256);                     // 8 MB
  unsigned char* pmask  = (unsigned char*)(ws + 256 + 8388608);   // 2 MB
  char* wb              = ws + 256 + 8388608 + 2097152;
  _Float16* w1kh = (_Float16*)(wb);                               // 16 KB
  _Float16* w1kl = (_Float16*)(wb + 16384);                       // 16 KB
  _Float16* w2h  = (_Float16*)(wb + 32768);                       //  4 KB
  _Float16* w2l  = (_Float16*)(wb + 36864);                       //  4 KB
  float* out = (float*)d_out;

  (void)hipMemsetAsync(mm, 0xFF, 128, stream);                // mins  -> +inf key
  (void)hipMemsetAsync((char*)mm + 128, 0x00, 128, stream);   // maxs  -> -inf key
  k_pm  <<<NMM + 160, 64, 0, stream>>>(x, w1, w2, mm, w1kh, w1kl, w2h, w2l);
  k_main<<<B*H*4, 64, 0, stream>>>(x, mr, mm, w1kh, w1kl, w2h, w2l, b1,
                                   out, alpha_n, pmask);
  k_life<<<B*H, 256, 0, stream>>>(alpha_n, pmask, out);
}

// Round 9
// 531.078 us; speedup vs baseline: 1.6775x; 1.6565x over previous
//
#include <hip/hip_runtime.h>

#define B 32
#define C 16
#define H 256
#define W 256
#define HID 128
#define HW (H*W)
#define MROWS 32
#define NMM 4096   // minmax blocks: 32*16*(256/32)

typedef __attribute__((ext_vector_type(8))) _Float16 f16x8;
typedef __attribute__((ext_vector_type(4))) float f32x4;

// ---- order-preserving float <-> uint key for atomic min/max ----
__device__ __forceinline__ unsigned fkey(float f){
  unsigned u = __float_as_uint(f);
  return (u & 0x80000000u) ? ~u : (u | 0x80000000u);
}
__device__ __forceinline__ float fkeyinv(unsigned k){
  unsigned u = (k & 0x80000000u) ? (k & 0x7FFFFFFFu) : ~k;
  return __uint_as_float(u);
}
__device__ __forceinline__ int pk2(_Float16 a, _Float16 b){
  union { _Float16 h[2]; int i; } u; u.h[0]=a; u.h[1]=b; return u.i;
}

// ---- fused prep (weight fragments) + per-channel Sobel min/max ----
// mm layout: [0..15]=gx_min [16..31]=gy_min [32..47]=gx_max [48..63]=gy_max
__global__ __launch_bounds__(64) void k_pm(
    const float* __restrict__ x, const float* __restrict__ w1,
    const float* __restrict__ w2, unsigned* __restrict__ mm,
    _Float16* __restrict__ w1kh, _Float16* __restrict__ w1kl,
    _Float16* __restrict__ w2h,  _Float16* __restrict__ w2l)
{
  const int tid = threadIdx.x;
  if (blockIdx.x >= NMM){
    int e = (blockIdx.x - NMM)*64 + tid;
    if (e < 8192){
      int j = e & 7, l = (e >> 3) & 63, otk = e >> 9;   // otk = ot*2+kb
      int o = 16*(otk >> 1) + (l & 15);
      int k = (otk & 1)*32 + 8*(l >> 4) + j;
      float v = (k < 48) ? w1[o*48 + k] : 0.f;
      _Float16 h = (_Float16)v;
      w1kh[e] = h; w1kl[e] = (_Float16)(v - (float)h);
    } else {
      int e2 = e - 8192;
      int j = e2 & 7, l = (e2 >> 3) & 63, s = e2 >> 9;
      float v = w2[(l & 15)*128 + 32*s + 8*(l >> 4) + j];
      _Float16 h = (_Float16)v;
      w2h[e2] = h; w2l[e2] = (_Float16)(v - (float)h);
    }
    return;
  }
  int chunk = blockIdx.x & 7, bc = blockIdx.x >> 3, c = bc & 15;
  const float* p = x + (size_t)bc * HW;
  const int j4 = tid * 4;
  const int i0 = chunk * MROWS;

  float Aw[6], Bw[6], Cw[6];
  auto loadrow = [&](int row, float* wv){
    float4 v = *(const float4*)(p + (size_t)row*W + j4);
    float l = __shfl(v.w, tid - 1);
    float r = __shfl(v.x, tid + 1);
    if (tid == 0)  l = 0.f;
    if (tid == 63) r = 0.f;
    wv[0]=l; wv[1]=v.x; wv[2]=v.y; wv[3]=v.z; wv[4]=v.w; wv[5]=r;
  };
  if (i0 > 0) loadrow(i0-1, Aw);
  else { for (int t=0;t<6;++t) Aw[t]=0.f; }
  loadrow(i0, Bw);

  float gxmn = 1e30f, gxmx = -1e30f, gymn = 1e30f, gymx = -1e30f;
  for (int r = 0; r < MROWS; ++r){
    int ipr = i0 + r + 1;
    if (ipr < H) loadrow(ipr, Cw);
    else { for (int t=0;t<6;++t) Cw[t]=0.f; }
    #pragma unroll
    for (int t = 0; t < 4; ++t){
      float gx = (Aw[t+2]-Aw[t] + 2.f*(Bw[t+2]-Bw[t]) + Cw[t+2]-Cw[t]) * 0.125f;
      float gy = (Cw[t]-Aw[t] + 2.f*(Cw[t+1]-Aw[t+1]) + Cw[t+2]-Aw[t+2]) * 0.125f;
      gxmn = fminf(gxmn, gx); gxmx = fmaxf(gxmx, gx);
      gymn = fminf(gymn, gy); gymx = fmaxf(gymx, gy);
    }
    #pragma unroll
    for (int t = 0; t < 6; ++t){ Aw[t] = Bw[t]; Bw[t] = Cw[t]; }
  }
  for (int off = 32; off; off >>= 1){
    gxmn = fminf(gxmn, __shfl_down(gxmn, off));
    gxmx = fmaxf(gxmx, __shfl_down(gxmx, off));
    gymn = fminf(gymn, __shfl_down(gymn, off));
    gymx = fmaxf(gymx, __shfl_down(gymx, off));
  }
  if (tid == 0){
    atomicMin(&mm[c],      fkey(gxmn));
    atomicMin(&mm[16+c],   fkey(gymn));
    atomicMax(&mm[32+c],   fkey(gxmx));
    atomicMax(&mm[48+c],   fkey(gymx));
  }
}

// ---- main: 2 waves / 128 px (half row); fragments REGISTER-RESIDENT ----
// (round-8 regression root-caused: per-g w1 fragment re-loads = 4.3 GB L2
//  demand -> L2 thrash -> 1.7 GB HBM fetch + 8x write-back amplification.
//  Fragments loaded ONCE per block here, like round 5 whose traffic was clean.)
__global__ __launch_bounds__(128) void k_main(
    const float* __restrict__ x, const float* __restrict__ mrand,
    const unsigned* __restrict__ mm,
    const _Float16* __restrict__ w1kh, const _Float16* __restrict__ w1kl,
    const _Float16* __restrict__ w2h,  const _Float16* __restrict__ w2l,
    const float* __restrict__ b1,
    float* __restrict__ out, float* __restrict__ alpha_new,
    unsigned char* __restrict__ premask)
{
  // row = 16 chunks of 16B, XOR-swizzled: phys = chunk ^ (px&15).
  // chunks 0..5: y hi (48 f16); 6..11: y lo; 12..15: x[0..15] as fp32.
  __shared__ __align__(16) _Float16 yl[128][128];   // 32 KB
  __shared__ float b1l[128];
  __shared__ float amn_x[16], inv_x[16], amn_y[16], inv_y[16];

  const int tid  = threadIdx.x;
  const int blk  = blockIdx.x;
  const int half = blk & 1;
  const int rowid = blk >> 1;              // b*H + i
  const int i = rowid & 255, b = rowid >> 8;
  const int j0 = half * 128;
  const int lane = tid & 63, wvid = tid >> 6;
  const int q = lane >> 4, n16 = lane & 15;

  if (tid < 16){
    int c = tid;
    float mn = fabsf(fkeyinv(mm[c]));
    float mx = fabsf(fkeyinv(mm[32+c]));
    float dv = mn + mx;
    amn_x[c] = mn; inv_x[c] = (dv == 0.f) ? 1.f : 1.f/dv;
    mn = fabsf(fkeyinv(mm[16+c]));
    mx = fabsf(fkeyinv(mm[48+c]));
    dv = mn + mx;
    amn_y[c] = mn; inv_y[c] = (dv == 0.f) ? 1.f : 1.f/dv;
  }
  b1l[tid] = b1[tid];
  __syncthreads();

  // ---- stencil: thread = pixel j0+tid; writes its own LDS row (tid) ----
  {
    const float* xb = x + (size_t)b * C * HW;
    const int j = j0 + tid;
    const int key = tid & 15;
    const int im = i-1, ipp = i+1;
    const bool iu = im >= 0, id = ipp < H, jl = j > 0, jr = j < W-1;
    float yv[48];
    float pre3 = 0.f;
    #pragma unroll
    for (int c = 0; c < 16; ++c){
      const float* pc = xb + (size_t)c * HW;
      const float* r0 = pc + (size_t)im*W;
      const float* r1 = pc + (size_t)i*W;
      const float* r2 = pc + (size_t)ipp*W;
      float v00 = (iu&&jl) ? r0[j-1] : 0.f;
      float v01 =  iu      ? r0[j]   : 0.f;
      float v02 = (iu&&jr) ? r0[j+1] : 0.f;
      float v10 =  jl      ? r1[j-1] : 0.f;
      float v11 =            r1[j];
      float v12 =  jr      ? r1[j+1] : 0.f;
      float v20 = (id&&jl) ? r2[j-1] : 0.f;
      float v21 =  id      ? r2[j]   : 0.f;
      float v22 = (id&&jr) ? r2[j+1] : 0.f;
      float gx = (v02 - v00 + 2.f*(v12 - v10) + v22 - v20) * 0.125f;
      float gy = (v20 - v00 + 2.f*(v21 - v01) + v22 - v02) * 0.125f;
      float gl = (v01 + v10 + v12 + v21 - 4.f*v11) * 0.125f;
      float gxn = (gx + amn_x[c]) * inv_x[c];
      float gyn = (gy + amn_y[c]) * inv_y[c];
      yv[c]    = v11;
      yv[16+c] = gl;
      yv[32+c] = sqrtf(gxn*gxn + gyn*gyn);
      if (c == 3){
        pre3 = fmaxf(fmaxf(fmaxf(v00,v01),fmaxf(v02,v10)),
               fmaxf(fmaxf(v11,v12),fmaxf(fmaxf(v20,v21),v22)));
      }
    }
    premask[(size_t)b*HW + (size_t)i*W + j] = (pre3 > 0.1f) ? 1 : 0;
    #pragma unroll
    for (int cb = 0; cb < 6; ++cb){
      f16x8 vh, vl;
      #pragma unroll
      for (int e = 0; e < 8; ++e){
        float v = yv[cb*8+e];
        _Float16 h = (_Float16)v;
        vh[e] = h; vl[e] = (_Float16)(v - (float)h);
      }
      *(f16x8*)&yl[tid][((cb    ) ^ key)*8] = vh;
      *(f16x8*)&yl[tid][((cb + 6) ^ key)*8] = vl;
    }
    #pragma unroll
    for (int t = 0; t < 4; ++t){
      union { float f[4]; f16x8 v; } u;
      #pragma unroll
      for (int e = 0; e < 4; ++e) u.f[e] = yv[4*t+e];
      *(f16x8*)&yl[tid][((12+t) ^ key)*8] = u.v;
    }
  }
  // y rows are wave-private (wave reads only rows [64*wvid, 64*wvid+64));
  // per-wave LDS ops are program-ordered -> no barrier needed here.

  // ---- A fragments: loaded ONCE, register-resident ----
  f16x8 A1h[8][2], A1l[8][2];
  #pragma unroll
  for (int ot = 0; ot < 8; ++ot){
    #pragma unroll
    for (int kb = 0; kb < 2; ++kb){
      A1h[ot][kb] = *(const f16x8*)(w1kh + (ot*2+kb)*512 + lane*8);
      A1l[ot][kb] = *(const f16x8*)(w1kl + (ot*2+kb)*512 + lane*8);
    }
  }
  f16x8 A2h[4], A2l[4];
  #pragma unroll
  for (int s = 0; s < 4; ++s){
    A2h[s] = *(const f16x8*)(w2h + s*512 + lane*8);
    A2l[s] = *(const f16x8*)(w2l + s*512 + lane*8);
  }

  const size_t rowbase = (size_t)b*C*HW + (size_t)i*W;
  const size_t abase   = (size_t)b*HW + (size_t)i*W;
  const float* mr_row  = mrand + abase + j0;
  const int srcA = 32*(q&1) + n16;
  const bool hiq = (q >= 2);

  // ---- per wave: 4 groups of 16 pixels ----
  #pragma unroll 1
  for (int g = 0; g < 4; ++g){
    const int pl = wvid*64 + g*16 + n16;      // local pixel / LDS row
    const int key = n16;                      // = pl & 15
    const _Float16* yr = yl[pl];
    f16x8 Bh0 = *(const f16x8*)&yr[(( q       ) ^ key)*8];
    f16x8 Bl0 = *(const f16x8*)&yr[(( 6+q     ) ^ key)*8];
    // k>=48 weights are zero; q>=2 lanes re-read a finite chunk (harmless)
    f16x8 Bh1 = *(const f16x8*)&yr[(( 4+(q&1) ) ^ key)*8];
    f16x8 Bl1 = *(const f16x8*)&yr[((10+(q&1) ) ^ key)*8];

    // GEMM1: h = relu(w1*y + b1), 4-product hi/lo (fp32 fidelity)
    int hh[8][2], hl[8][2];
    #pragma unroll
    for (int ot = 0; ot < 8; ++ot){
      f32x4 acc = *(const f32x4*)&b1l[16*ot + 4*q];
      acc = __builtin_amdgcn_mfma_f32_16x16x32_f16(A1h[ot][0], Bh0, acc, 0, 0, 0);
      acc = __builtin_amdgcn_mfma_f32_16x16x32_f16(A1h[ot][0], Bl0, acc, 0, 0, 0);
      acc = __builtin_amdgcn_mfma_f32_16x16x32_f16(A1l[ot][0], Bh0, acc, 0, 0, 0);
      acc = __builtin_amdgcn_mfma_f32_16x16x32_f16(A1l[ot][0], Bl0, acc, 0, 0, 0);
      acc = __builtin_amdgcn_mfma_f32_16x16x32_f16(A1h[ot][1], Bh1, acc, 0, 0, 0);
      acc = __builtin_amdgcn_mfma_f32_16x16x32_f16(A1h[ot][1], Bl1, acc, 0, 0, 0);
      acc = __builtin_amdgcn_mfma_f32_16x16x32_f16(A1l[ot][1], Bh1, acc, 0, 0, 0);
      acc = __builtin_amdgcn_mfma_f32_16x16x32_f16(A1l[ot][1], Bl1, acc, 0, 0, 0);
      float h0 = fmaxf(acc[0],0.f), h1 = fmaxf(acc[1],0.f);
      float h2 = fmaxf(acc[2],0.f), h3 = fmaxf(acc[3],0.f);
      _Float16 a0=(_Float16)h0, a1=(_Float16)h1, a2=(_Float16)h2, a3=(_Float16)h3;
      hh[ot][0] = pk2(a0, a1);
      hh[ot][1] = pk2(a2, a3);
      hl[ot][0] = pk2((_Float16)(h0-(float)a0), (_Float16)(h1-(float)a1));
      hl[ot][1] = pk2((_Float16)(h2-(float)a2), (_Float16)(h3-(float)a3));
    }

    // GEMM2: dx = w2*h; B-fragments built via in-wave shuffles (no LDS)
    f32x4 d2 = {0.f, 0.f, 0.f, 0.f};
    #pragma unroll
    for (int s = 0; s < 4; ++s){
      int e0 = __shfl(hh[2*s  ][0], srcA),    e1 = __shfl(hh[2*s  ][1], srcA);
      int f0 = __shfl(hh[2*s+1][0], srcA),    f1 = __shfl(hh[2*s+1][1], srcA);
      int g0 = __shfl(hh[2*s  ][0], srcA+16), g1 = __shfl(hh[2*s  ][1], srcA+16);
      int k0 = __shfl(hh[2*s+1][0], srcA+16), k1 = __shfl(hh[2*s+1][1], srcA+16);
      union { int d[4]; f16x8 v; } bh;
      bh.d[0] = hiq ? f0 : e0; bh.d[1] = hiq ? f1 : e1;
      bh.d[2] = hiq ? k0 : g0; bh.d[3] = hiq ? k1 : g1;
      e0 = __shfl(hl[2*s  ][0], srcA);    e1 = __shfl(hl[2*s  ][1], srcA);
      f0 = __shfl(hl[2*s+1][0], srcA);    f1 = __shfl(hl[2*s+1][1], srcA);
      g0 = __shfl(hl[2*s  ][0], srcA+16); g1 = __shfl(hl[2*s  ][1], srcA+16);
      k0 = __shfl(hl[2*s+1][0], srcA+16); k1 = __shfl(hl[2*s+1][1], srcA+16);
      union { int d[4]; f16x8 v; } bl;
      bl.d[0] = hiq ? f0 : e0; bl.d[1] = hiq ? f1 : e1;
      bl.d[2] = hiq ? k0 : g0; bl.d[3] = hiq ? k1 : g1;
      d2 = __builtin_amdgcn_mfma_f32_16x16x32_f16(A2h[s], bh.v, d2, 0, 0, 0);
      d2 = __builtin_amdgcn_mfma_f32_16x16x32_f16(A2h[s], bl.v, d2, 0, 0, 0);
      d2 = __builtin_amdgcn_mfma_f32_16x16x32_f16(A2l[s], bh.v, d2, 0, 0, 0);
      d2 = __builtin_amdgcn_mfma_f32_16x16x32_f16(A2l[s], bl.v, d2, 0, 0, 0);
    }

    // epilogue: exact fp32 x from LDS chunks 12..15
    union { f16x8 v; float f[4]; } xu;
    xu.v = *(const f16x8*)&yr[((12+q) ^ key)*8];
    const float fire = (mr_row[pl] <= 0.5f) ? 1.f : 0.f;
    #pragma unroll
    for (int r = 0; r < 4; ++r)
      out[rowbase + (size_t)(4*q+r)*HW + (j0 + pl)] = xu.f[r] + d2[r]*fire;
    if (q == 0) alpha_new[abase + j0 + pl] = xu.f[3] + d2[3]*fire;
  }
}

// ---- life: pre-mask (from k_main) AND pooled(alpha_new) > 0.1 ----
__global__ __launch_bounds__(256) void k_life(
    const float* __restrict__ alpha_new,
    const unsigned char* __restrict__ premask,
    float* __restrict__ out)
{
  __shared__ float lds[258];
  const int i = blockIdx.x & 255, b = blockIdx.x >> 8;
  const int j = threadIdx.x;
  const float* an = alpha_new + (size_t)b*HW;
  float m = an[(size_t)i*W + j];
  if (i > 0)   m = fmaxf(m, an[(size_t)(i-1)*W + j]);
  if (i < 255) m = fmaxf(m, an[(size_t)(i+1)*W + j]);
  if (j == 0){ lds[0] = 0.f; lds[257] = 0.f; }
  lds[j+1] = m;
  __syncthreads();
  float pooled = fmaxf(fmaxf(lds[j], lds[j+1]), lds[j+2]);
  bool life = (premask[(size_t)b*HW + (size_t)i*W + j] != 0) && (pooled > 0.1f);
  if (!life){
    size_t px = (size_t)b*C*HW + (size_t)i*W + j;
    #pragma unroll
    for (int c = 0; c < 16; ++c) out[px + (size_t)c*HW] = 0.f;
  }
}

extern "C" void kernel_launch(void* const* d_in, const int* in_sizes, int n_in,
                              void* d_out, int out_size, void* d_ws, size_t ws_size,
                              hipStream_t stream) {
  const float* x  = (const float*)d_in[0];
  const float* w1 = (const float*)d_in[1];
  const float* b1 = (const float*)d_in[2];
  const float* w2 = (const float*)d_in[3];
  const float* mr = (const float*)d_in[4];

  char* ws = (char*)d_ws;
  unsigned* mm          = (unsigned*)ws;                          // 256 B
  float* alpha_n        = (float*)(ws + 256);                     // 8 MB
  unsigned char* pmask  = (unsigned char*)(ws + 256 + 8388608);   // 2 MB
  char* wb              = ws + 256 + 8388608 + 2097152;
  _Float16* w1kh = (_Float16*)(wb);                               // 16 KB
  _Float16* w1kl = (_Float16*)(wb + 16384);                       // 16 KB
  _Float16* w2h  = (_Float16*)(wb + 32768);                       //  4 KB
  _Float16* w2l  = (_Float16*)(wb + 36864);                       //  4 KB
  float* out = (float*)d_out;

  (void)hipMemsetAsync(mm, 0xFF, 128, stream);                // mins -> +inf key
  (void)hipMemsetAsync((char*)mm + 128, 0x00, 128, stream);   // maxs -> -inf key
  k_pm  <<<NMM + 160, 64, 0, stream>>>(x, w1, w2, mm, w1kh, w1kl, w2h, w2l);
  k_main<<<B*H*2, 128, 0, stream>>>(x, mr, mm, w1kh, w1kl, w2h, w2l, b1,
                                    out, alpha_n, pmask);
  k_life<<<B*H, 256, 0, stream>>>(alpha_n, pmask, out);
}

// Round 10
// 351.271 us; speedup vs baseline: 2.5362x; 1.5119x over previous
//
#include <hip/hip_runtime.h>

#define B 32
#define C 16
#define H 256
#define W 256
#define HID 128
#define HW (H*W)
#define MROWS 32
#define NMM 4096   // minmax blocks: 32*16*(256/32)

typedef __attribute__((ext_vector_type(8))) _Float16 f16x8;
typedef __attribute__((ext_vector_type(4))) _Float16 f16x4;
typedef __attribute__((ext_vector_type(4))) float f32x4;

// ---- order-preserving float <-> uint key for atomic min/max ----
__device__ __forceinline__ unsigned fkey(float f){
  unsigned u = __float_as_uint(f);
  return (u & 0x80000000u) ? ~u : (u | 0x80000000u);
}
__device__ __forceinline__ float fkeyinv(unsigned k){
  unsigned u = (k & 0x80000000u) ? (k & 0x7FFFFFFFu) : ~k;
  return __uint_as_float(u);
}
__device__ __forceinline__ int pk2(_Float16 a, _Float16 b){
  union { _Float16 h[2]; int i; } u; u.h[0]=a; u.h[1]=b; return u.i;
}
// chunk swizzle: G0 = chunks 0..7 XOR (key&7); G1 = chunks 8..11 XOR (key&3)
__device__ __forceinline__ int physc(int c, int key){
  return (c < 8) ? (c ^ (key & 7)) : (8 + ((c & 3) ^ (key & 3)));
}

// ---- fused prep (weight fragments) + per-channel Sobel min/max ----
// mm layout: [0..15]=gx_min [16..31]=gy_min [32..47]=gx_max [48..63]=gy_max
__global__ __launch_bounds__(64) void k_pm(
    const float* __restrict__ x, const float* __restrict__ w1,
    const float* __restrict__ w2, unsigned* __restrict__ mm,
    _Float16* __restrict__ w1kh, _Float16* __restrict__ w1kl,
    _Float16* __restrict__ w1k1h, _Float16* __restrict__ w1k1l,
    _Float16* __restrict__ w2h)
{
  const int tid = threadIdx.x;
  if (blockIdx.x >= NMM){
    int e = (blockIdx.x - NMM)*64 + tid;
    if (e < 4096){
      // w1 k=0..31, x32 A frags: lane l -> M=l&15, K=8*(l>>4)+j
      int j = e & 7, l = (e >> 3) & 63, ot = e >> 9;
      float v = w1[(16*ot + (l & 15))*48 + 8*(l >> 4) + j];
      _Float16 h = (_Float16)v;
      w1kh[e] = h; w1kl[e] = (_Float16)(v - (float)h);
    } else if (e < 6144){
      // w1 k=32..47, x16 A frags: lane l -> M=l&15, K=4*(l>>4)+j
      int e2 = e - 4096;
      int j = e2 & 3, l = (e2 >> 2) & 63, ot = e2 >> 8;
      float v = w1[(16*ot + (l & 15))*48 + 32 + 4*(l >> 4) + j];
      _Float16 h = (_Float16)v;
      w1k1h[e2] = h; w1k1l[e2] = (_Float16)(v - (float)h);
    } else if (e < 8192){
      // w2 hi-only x32 A frags
      int e2 = e - 6144;
      int j = e2 & 7, l = (e2 >> 3) & 63, s = e2 >> 9;
      w2h[e2] = (_Float16)w2[(l & 15)*128 + 32*s + 8*(l >> 4) + j];
    }
    return;
  }
  int chunk = blockIdx.x & 7, bc = blockIdx.x >> 3, c = bc & 15;
  const float* p = x + (size_t)bc * HW;
  const int j4 = tid * 4;
  const int i0 = chunk * MROWS;

  float Aw[6], Bw[6], Cw[6];
  auto loadrow = [&](int row, float* wv){
    float4 v = *(const float4*)(p + (size_t)row*W + j4);
    float l = __shfl(v.w, tid - 1);
    float r = __shfl(v.x, tid + 1);
    if (tid == 0)  l = 0.f;
    if (tid == 63) r = 0.f;
    wv[0]=l; wv[1]=v.x; wv[2]=v.y; wv[3]=v.z; wv[4]=v.w; wv[5]=r;
  };
  if (i0 > 0) loadrow(i0-1, Aw);
  else { for (int t=0;t<6;++t) Aw[t]=0.f; }
  loadrow(i0, Bw);

  float gxmn = 1e30f, gxmx = -1e30f, gymn = 1e30f, gymx = -1e30f;
  for (int r = 0; r < MROWS; ++r){
    int ipr = i0 + r + 1;
    if (ipr < H) loadrow(ipr, Cw);
    else { for (int t=0;t<6;++t) Cw[t]=0.f; }
    #pragma unroll
    for (int t = 0; t < 4; ++t){
      float gx = (Aw[t+2]-Aw[t] + 2.f*(Bw[t+2]-Bw[t]) + Cw[t+2]-Cw[t]) * 0.125f;
      float gy = (Cw[t]-Aw[t] + 2.f*(Cw[t+1]-Aw[t+1]) + Cw[t+2]-Aw[t+2]) * 0.125f;
      gxmn = fminf(gxmn, gx); gxmx = fmaxf(gxmx, gx);
      gymn = fminf(gymn, gy); gymx = fmaxf(gymx, gy);
    }
    #pragma unroll
    for (int t = 0; t < 6; ++t){ Aw[t] = Bw[t]; Bw[t] = Cw[t]; }
  }
  for (int off = 32; off; off >>= 1){
    gxmn = fminf(gxmn, __shfl_down(gxmn, off));
    gxmx = fmaxf(gxmx, __shfl_down(gxmx, off));
    gymn = fminf(gymn, __shfl_down(gymn, off));
    gymx = fmaxf(gymx, __shfl_down(gymx, off));
  }
  if (tid == 0){
    atomicMin(&mm[c],      fkey(gxmn));
    atomicMin(&mm[16+c],   fkey(gymn));
    atomicMax(&mm[32+c],   fkey(gxmx));
    atomicMax(&mm[48+c],   fkey(gymx));
  }
}

// ---- main: 1 wave / 64 px; small LDS + lean fragments for occupancy ----
// GEMM1: 4-product hi/lo (fp32-fidelity h). GEMM2: hi-only MFMA for channels,
// plus EXACT fp32 dx[alpha] via per-lane w2-row-3 dot + shfl_xor reduce.
__global__ __launch_bounds__(64) void k_main(
    const float* __restrict__ x, const float* __restrict__ mrand,
    const unsigned* __restrict__ mm,
    const _Float16* __restrict__ w1kh, const _Float16* __restrict__ w1kl,
    const _Float16* __restrict__ w1k1h, const _Float16* __restrict__ w1k1l,
    const _Float16* __restrict__ w2h, const float* __restrict__ w2f,
    const float* __restrict__ b1,
    float* __restrict__ out, float* __restrict__ alpha_new,
    unsigned char* __restrict__ premask)
{
  // 13-chunk rows (208B, 16B-aligned): chunks 0..5 = y hi, 6..11 = y lo, 12 pad
  __shared__ __align__(16) _Float16 yl[64][104];   // 13.3 KB
  __shared__ float amn_x[16], inv_x[16], amn_y[16], inv_y[16];

  const int tid = threadIdx.x;
  const int blk = blockIdx.x;                  // natural order
  const int quarter = blk & 3;
  const int rowid = blk >> 2;                  // b*H + i
  const int i = rowid & 255, b = rowid >> 8;
  const int j0 = quarter << 6;
  const int q = tid >> 4, n16 = tid & 15;

  if (tid < 16){
    int c = tid;
    float mn = fabsf(fkeyinv(mm[c]));
    float mx = fabsf(fkeyinv(mm[32+c]));
    float dv = mn + mx;
    amn_x[c] = mn; inv_x[c] = (dv == 0.f) ? 1.f : 1.f/dv;
    mn = fabsf(fkeyinv(mm[16+c]));
    mx = fabsf(fkeyinv(mm[48+c]));
    dv = mn + mx;
    amn_y[c] = mn; inv_y[c] = (dv == 0.f) ? 1.f : 1.f/dv;
  }
  // single-wave block: LDS ops are program-ordered, no barrier needed

  // ---- stencil: thread = pixel j0+tid, per-8-channel halves ----
  {
    const float* xb = x + (size_t)b * C * HW;
    const int j = j0 + tid;
    const int key = tid & 15;
    const int im = i-1, ipp = i+1;
    const bool iu = im >= 0, id = ipp < H, jl = j > 0, jr = j < W-1;
    #pragma unroll
    for (int hp = 0; hp < 2; ++hp){
      float xv[8], lv[8], mv[8];
      #pragma unroll
      for (int cc = 0; cc < 8; ++cc){
        const int c = hp*8 + cc;
        const float* pc = xb + (size_t)c * HW;
        const float* r0 = pc + (size_t)im*W;
        const float* r1 = pc + (size_t)i*W;
        const float* r2 = pc + (size_t)ipp*W;
        float v00 = (iu&&jl) ? r0[j-1] : 0.f;
        float v01 =  iu      ? r0[j]   : 0.f;
        float v02 = (iu&&jr) ? r0[j+1] : 0.f;
        float v10 =  jl      ? r1[j-1] : 0.f;
        float v11 =            r1[j];
        float v12 =  jr      ? r1[j+1] : 0.f;
        float v20 = (id&&jl) ? r2[j-1] : 0.f;
        float v21 =  id      ? r2[j]   : 0.f;
        float v22 = (id&&jr) ? r2[j+1] : 0.f;
        float gx = (v02 - v00 + 2.f*(v12 - v10) + v22 - v20) * 0.125f;
        float gy = (v20 - v00 + 2.f*(v21 - v01) + v22 - v02) * 0.125f;
        float gl = (v01 + v10 + v12 + v21 - 4.f*v11) * 0.125f;
        float gxn = (gx + amn_x[c]) * inv_x[c];
        float gyn = (gy + amn_y[c]) * inv_y[c];
        xv[cc] = v11;
        lv[cc] = gl;
        mv[cc] = sqrtf(gxn*gxn + gyn*gyn);
        if (hp == 0 && cc == 3){
          float pre3 = fmaxf(fmaxf(fmaxf(v00,v01),fmaxf(v02,v10)),
                       fmaxf(fmaxf(v11,v12),fmaxf(fmaxf(v20,v21),v22)));
          premask[(size_t)b*HW + (size_t)i*W + j] = (pre3 > 0.1f) ? 1 : 0;
        }
      }
      f16x8 vh, vl;
      #pragma unroll
      for (int e = 0; e < 8; ++e){ _Float16 h=(_Float16)xv[e]; vh[e]=h; vl[e]=(_Float16)(xv[e]-(float)h); }
      *(f16x8*)&yl[tid][physc(hp,    key)*8] = vh;
      *(f16x8*)&yl[tid][physc(6+hp,  key)*8] = vl;
      #pragma unroll
      for (int e = 0; e < 8; ++e){ _Float16 h=(_Float16)lv[e]; vh[e]=h; vl[e]=(_Float16)(lv[e]-(float)h); }
      *(f16x8*)&yl[tid][physc(2+hp,  key)*8] = vh;
      *(f16x8*)&yl[tid][physc(8+hp,  key)*8] = vl;
      #pragma unroll
      for (int e = 0; e < 8; ++e){ _Float16 h=(_Float16)mv[e]; vh[e]=h; vl[e]=(_Float16)(mv[e]-(float)h); }
      *(f16x8*)&yl[tid][physc(4+hp,  key)*8] = vh;
      *(f16x8*)&yl[tid][physc(10+hp, key)*8] = vl;
    }
  }

  // ---- resident fragments: A1 x32 hi/lo (64 VGPR) + A2 hi (16 VGPR) ----
  f16x8 A1h[8], A1l[8];
  #pragma unroll
  for (int ot = 0; ot < 8; ++ot){
    A1h[ot] = *(const f16x8*)(w1kh + ot*512 + tid*8);
    A1l[ot] = *(const f16x8*)(w1kl + ot*512 + tid*8);
  }
  f16x8 A2h[4];
  #pragma unroll
  for (int s = 0; s < 4; ++s)
    A2h[s] = *(const f16x8*)(w2h + s*512 + tid*8);

  const size_t rowbase = (size_t)b*C*HW + (size_t)i*W;
  const size_t abase   = (size_t)b*HW + (size_t)i*W;
  const float* mr_row  = mrand + abase + j0;
  const float* w2r3    = w2f + 3*HID;
  const int srcA = 32*(q&1) + n16;
  const bool hiq = (q >= 2);

  // ---- 4 groups of 16 pixels ----
  #pragma unroll 1
  for (int g = 0; g < 4; ++g){
    const int pl = g*16 + n16;                // local pixel / LDS row
    const int key = n16;                      // = pl & 15
    const _Float16* yr = yl[pl];
    f16x8 Bh0 = *(const f16x8*)&yr[physc(q,     key)*8];
    f16x8 Bl0 = *(const f16x8*)&yr[physc(6+q,   key)*8];
    f16x4 Bh1 = *(const f16x4*)&yr[physc(4+(q>>1),  key)*8 + 4*(q&1)];
    f16x4 Bl1 = *(const f16x4*)&yr[physc(10+(q>>1), key)*8 + 4*(q&1)];

    // GEMM1: h = relu(w1*y + b1); 4-product hi/lo over K=32 (x32) + K=16 (x16)
    int hh[8][2];
    float partial3 = 0.f;
    #pragma unroll
    for (int ot = 0; ot < 8; ++ot){
      f16x4 A1h1 = *(const f16x4*)(w1k1h + ot*256 + tid*4);   // L1-hot 4KB
      f16x4 A1l1 = *(const f16x4*)(w1k1l + ot*256 + tid*4);
      f32x4 acc = *(const f32x4*)(b1 + 16*ot + 4*q);          // L1-hot
      acc = __builtin_amdgcn_mfma_f32_16x16x32_f16(A1h[ot], Bh0, acc, 0, 0, 0);
      acc = __builtin_amdgcn_mfma_f32_16x16x32_f16(A1h[ot], Bl0, acc, 0, 0, 0);
      acc = __builtin_amdgcn_mfma_f32_16x16x32_f16(A1l[ot], Bh0, acc, 0, 0, 0);
      acc = __builtin_amdgcn_mfma_f32_16x16x32_f16(A1l[ot], Bl0, acc, 0, 0, 0);
      acc = __builtin_amdgcn_mfma_f32_16x16x16f16(A1h1, Bh1, acc, 0, 0, 0);
      acc = __builtin_amdgcn_mfma_f32_16x16x16f16(A1h1, Bl1, acc, 0, 0, 0);
      acc = __builtin_amdgcn_mfma_f32_16x16x16f16(A1l1, Bh1, acc, 0, 0, 0);
      acc = __builtin_amdgcn_mfma_f32_16x16x16f16(A1l1, Bl1, acc, 0, 0, 0);
      float h0 = fmaxf(acc[0],0.f), h1 = fmaxf(acc[1],0.f);
      float h2 = fmaxf(acc[2],0.f), h3 = fmaxf(acc[3],0.f);
      hh[ot][0] = pk2((_Float16)h0, (_Float16)h1);
      hh[ot][1] = pk2((_Float16)h2, (_Float16)h3);
      // exact fp32 alpha path: partial dot with w2 row 3 (L1-hot 512B)
      f32x4 w3 = *(const f32x4*)(w2r3 + 16*ot + 4*q);
      partial3 = fmaf(w3[0],h0, fmaf(w3[1],h1, fmaf(w3[2],h2, fmaf(w3[3],h3, partial3))));
    }
    // reduce partial3 across the 4 q-groups (lanes n16, n16+16, n16+32, n16+48)
    partial3 += __shfl_xor(partial3, 16);
    partial3 += __shfl_xor(partial3, 32);      // dx[3] for pixel n16, all lanes

    // GEMM2 (hi-only): dx = w2h * h_hi; B via in-wave shuffles
    f32x4 d2 = {0.f, 0.f, 0.f, 0.f};
    #pragma unroll
    for (int s = 0; s < 4; ++s){
      int e0 = __shfl(hh[2*s  ][0], srcA),    e1 = __shfl(hh[2*s  ][1], srcA);
      int f0 = __shfl(hh[2*s+1][0], srcA),    f1 = __shfl(hh[2*s+1][1], srcA);
      int g0 = __shfl(hh[2*s  ][0], srcA+16), g1 = __shfl(hh[2*s  ][1], srcA+16);
      int k0 = __shfl(hh[2*s+1][0], srcA+16), k1 = __shfl(hh[2*s+1][1], srcA+16);
      union { int d[4]; f16x8 v; } bh;
      bh.d[0] = hiq ? f0 : e0; bh.d[1] = hiq ? f1 : e1;
      bh.d[2] = hiq ? k0 : g0; bh.d[3] = hiq ? k1 : g1;
      d2 = __builtin_amdgcn_mfma_f32_16x16x32_f16(A2h[s], bh.v, d2, 0, 0, 0);
    }

    // epilogue: x re-read from global (L1/L2-hot; proven no HBM penalty, r5)
    const float fire = (mr_row[pl] <= 0.5f) ? 1.f : 0.f;
    float a3v = 0.f;
    #pragma unroll
    for (int r = 0; r < 4; ++r){
      const int c = 4*q + r;
      const size_t idx = rowbase + (size_t)c*HW + (j0 + pl);
      const float xv = x[idx];
      const float dxv = (c == 3) ? partial3 : d2[r];
      const float val = xv + dxv*fire;
      out[idx] = val;
      if (c == 3) a3v = val;
    }
    if (q == 0) alpha_new[abase + j0 + pl] = a3v;
  }
}

// ---- life: pre-mask (from k_main) AND pooled(alpha_new) > 0.1 ----
__global__ __launch_bounds__(256) void k_life(
    const float* __restrict__ alpha_new,
    const unsigned char* __restrict__ premask,
    float* __restrict__ out)
{
  __shared__ float lds[258];
  const int i = blockIdx.x & 255, b = blockIdx.x >> 8;
  const int j = threadIdx.x;
  const float* an = alpha_new + (size_t)b*HW;
  float m = an[(size_t)i*W + j];
  if (i > 0)   m = fmaxf(m, an[(size_t)(i-1)*W + j]);
  if (i < 255) m = fmaxf(m, an[(size_t)(i+1)*W + j]);
  if (j == 0){ lds[0] = 0.f; lds[257] = 0.f; }
  lds[j+1] = m;
  __syncthreads();
  float pooled = fmaxf(fmaxf(lds[j], lds[j+1]), lds[j+2]);
  bool life = (premask[(size_t)b*HW + (size_t)i*W + j] != 0) && (pooled > 0.1f);
  if (!life){
    size_t px = (size_t)b*C*HW + (size_t)i*W + j;
    #pragma unroll
    for (int c = 0; c < 16; ++c) out[px + (size_t)c*HW] = 0.f;
  }
}

extern "C" void kernel_launch(void* const* d_in, const int* in_sizes, int n_in,
                              void* d_out, int out_size, void* d_ws, size_t ws_size,
                              hipStream_t stream) {
  const float* x  = (const float*)d_in[0];
  const float* w1 = (const float*)d_in[1];
  const float* b1 = (const float*)d_in[2];
  const float* w2 = (const float*)d_in[3];
  const float* mr = (const float*)d_in[4];

  char* ws = (char*)d_ws;
  unsigned* mm          = (unsigned*)ws;                          // 256 B
  float* alpha_n        = (float*)(ws + 256);                     // 8 MB
  unsigned char* pmask  = (unsigned char*)(ws + 256 + 8388608);   // 2 MB
  char* wb              = ws + 256 + 8388608 + 2097152;
  _Float16* w1kh  = (_Float16*)(wb);                              // 8 KB
  _Float16* w1kl  = (_Float16*)(wb + 8192);                       // 8 KB
  _Float16* w1k1h = (_Float16*)(wb + 16384);                      // 4 KB
  _Float16* w1k1l = (_Float16*)(wb + 20480);                      // 4 KB
  _Float16* w2h   = (_Float16*)(wb + 24576);                      // 4 KB
  float* out = (float*)d_out;

  (void)hipMemsetAsync(mm, 0xFF, 128, stream);                // mins -> +inf key
  (void)hipMemsetAsync((char*)mm + 128, 0x00, 128, stream);   // maxs -> -inf key
  k_pm  <<<NMM + 128, 64, 0, stream>>>(x, w1, w2, mm, w1kh, w1kl,
                                       w1k1h, w1k1l, w2h);
  k_main<<<B*H*4, 64, 0, stream>>>(x, mr, mm, w1kh, w1kl, w1k1h, w1k1l,
                                   w2h, w2, b1, out, alpha_n, pmask);
  k_life<<<B*H, 256, 0, stream>>>(alpha_n, pmask, out);
}